// Round 19
// baseline (227.803 us; speedup 1.0000x reference)
//
#include <hip/hip_runtime.h>
#include <hip/hip_bf16.h>
#include <stdint.h>

#define NA 131072
#define HD 256
#define NF 4096
#define MINFRAG 3
#define LN_EPS 1e-5f
#define NEPS 1e-12f

// ---- workspace layout (bytes) ----
// zeroed region [0, ZERO_BYTES) via k_prep (fused zero, 2069 blocks)
#define OFF_CNT    0ull          // NF i32
#define OFF_VSUM   16384ull      // NF f32
#define OFF_VFSUM  32768ull      // NF f32
#define OFF_NVSUM  49152ull      // NF f32
#define OFF_FILL   65536ull      // NF i32
#define OFF_DBL    81920ull      // unused (layout keep)
#define OFF_SSUM   86016ull      // NF*HD f32 = 4194304
#define OFF_NSUM   4280320ull    // NF*HD f32 = 4194304
#define ZERO_BYTES 8474624ull    // = 529664 float4 = 2069*256
// non-zeroed
#define OFF_OFFS   8474624ull    // NF i32
#define OFF_SVEC   8491008ull    // HD f32
#define OFF_C0     8492032ull    // HD f32
#define OFF_W0     8493056ull    // 1 f32
#define OFF_GBF    8493568ull    // HD*HD bf16 = 131072
#define OFF_ORDER  8624640ull    // NA i32 = 524288
#define OFF_PART   9150464ull    // FRAGB * PSTRIDE doubles
// total: 9,691,136 bytes

#define IDX_TRACE 257
#define IDX_DEVS  258
#define IDX_DEVV  259
#define IDX_VCNT  260
#define FRAGB 256
#define PSTRIDE 264

typedef __attribute__((ext_vector_type(8))) short short8;
typedef __attribute__((ext_vector_type(4))) float f32x4;
union F4S8 { float4 f; short8 s; };
union BFU { __hip_bfloat16 b; unsigned short u; };

__device__ __forceinline__ unsigned short f2b(float x) {
    BFU t; t.b = __float2bfloat16(x); return t.u;
}
__device__ __forceinline__ float b2f(unsigned short u) {
    return __uint_as_float(((uint32_t)u) << 16);
}
// fast silu: native v_exp + v_rcp (rel err ~1e-7, error budget ~1e-2)
__device__ __forceinline__ float silu_f(float x) {
    return x * __builtin_amdgcn_rcpf(1.f + __expf(-x));
}

// ---------------- prep (+ fused workspace zero), 2069 blocks ---------------
__global__ __launch_bounds__(256) void k_prep(
    const float* __restrict__ W1, const float* __restrict__ gamma,
    const float* __restrict__ beta, const float* __restrict__ b1,
    const float* __restrict__ Wv,
    unsigned short* __restrict__ Gbf, float* __restrict__ svec,
    float* __restrict__ c0, float* __restrict__ w0, float4* __restrict__ z) {
    __shared__ float red[8];
    int o = blockIdx.x;       // 2069 blocks
    int t = threadIdx.x;
    {   // zero [0, ZERO_BYTES): 2069*256 float4 exactly
        float4 zv = {0.f, 0.f, 0.f, 0.f};
        z[o * 256 + t] = zv;
    }
    if (o < HD) {
        float w = W1[(size_t)o * HD + t];
        unsigned short gb = f2b(w * gamma[t]);
        Gbf[(size_t)o * HD + t] = gb;
        float sp = b2f(gb);
        float cp = w * beta[t];
#pragma unroll
        for (int m = 32; m; m >>= 1) { sp += __shfl_xor(sp, m, 64); cp += __shfl_xor(cp, m, 64); }
        int wv = t >> 6;
        if ((t & 63) == 0) { red[wv] = sp; red[4 + wv] = cp; }
        __syncthreads();
        if (t == 0) {
            svec[o] = red[0] + red[1] + red[2] + red[3];
            c0[o]   = red[4] + red[5] + red[6] + red[7] + b1[o];
        }
    } else if (o == HD) {
        float v = Wv[t];
#pragma unroll
        for (int m = 32; m; m >>= 1) v += __shfl_xor(v, m, 64);
        int wv = t >> 6;
        if ((t & 63) == 0) red[wv] = v;
        __syncthreads();
        if (t == 0) w0[0] = red[0] + red[1] + red[2] + red[3];
    }
}

// ---------------- hist: fragment counts from fid only ----------------
__global__ __launch_bounds__(256) void k_hist(
    const int* __restrict__ fid, int* __restrict__ cnt) {
    int i = blockIdx.x * 256 + threadIdx.x;
    if (i < NA) atomicAdd(&cnt[fid[i]], 1);
}

// ---------------- scan ----------------
__global__ __launch_bounds__(256) void k_scan(const int* __restrict__ cnt,
                                              int* __restrict__ offs) {
    __shared__ int wsum[4];
    int t = threadIdx.x;
    int base = t * 16;
    int c[16];
    int tot = 0;
#pragma unroll
    for (int j = 0; j < 16; ++j) { c[j] = cnt[base + j]; tot += c[j]; }
    int lane = t & 63, w = t >> 6;
    int v = tot;
#pragma unroll
    for (int d = 1; d < 64; d <<= 1) {
        int o = __shfl_up(v, d, 64);
        if (lane >= d) v += o;
    }
    if (lane == 63) wsum[w] = v;
    __syncthreads();
    int wbase = 0;
    for (int i = 0; i < w; ++i) wbase += wsum[i];
    int run = wbase + v - tot;
#pragma unroll
    for (int j = 0; j < 16; ++j) { offs[base + j] = run; run += c[j]; }
}

// ---------------- scatter ----------------
__global__ __launch_bounds__(256) void k_scatter(
    const int* __restrict__ fid, const int* __restrict__ offs,
    int* __restrict__ fill, int* __restrict__ order) {
    int i = blockIdx.x * blockDim.x + threadIdx.x;
    if (i < NA) {
        int f = fid[i];
        int p = atomicAdd(&fill[f], 1);
        order[offs[f] + p] = i;
    }
}

// ---- merged: odd blocks = vec-stats (64 seq atoms); even = GEMM tile ----
__global__ __launch_bounds__(256) void k_merged(
    const float* __restrict__ A, const unsigned short* __restrict__ Gbf,
    const float* __restrict__ svec, const float* __restrict__ c0,
    const float* __restrict__ vs, const float* __restrict__ w0p,
    const int* __restrict__ order, const int* __restrict__ fid,
    const int* __restrict__ offs, const int* __restrict__ cnt,
    float* __restrict__ vsum, float* __restrict__ vfsum,
    float* __restrict__ nvsum,
    float* __restrict__ ssum, float* __restrict__ nsum) {
    __shared__ float4 As16[64 * 32];    // 32 KB: full A tile bf16, xor-swizzled
    __shared__ float muS[64], rsS[64], rnS[64];
    __shared__ float sqL[64][4];
    __shared__ int ridS[64], fragS[64];

    int tid = threadIdx.x;
    int lane = tid & 63, wid = tid >> 6;
    int b = blockIdx.x;

    if (b & 1) {
        // ---------------- stats role: 64 sequential atoms ----------------
        int g = lane >> 4, sl = lane & 15;
        float w0 = w0p[0];
        int base = (b >> 1) * 64 + wid * 16;
#pragma unroll 1
        for (int it = 0; it < 4; ++it) {
            int i = base + it * 4 + g;
            const float* vb = vs + (size_t)i * 3 * HD;
            float q0 = 0.f, q1 = 0.f, q2 = 0.f;
#pragma unroll
            for (int j = 0; j < 4; ++j) {
                float4 a = ((const float4*)(vb))[j * 16 + sl];
                float4 bb = ((const float4*)(vb + HD))[j * 16 + sl];
                float4 c = ((const float4*)(vb + 2 * HD))[j * 16 + sl];
                q0 += a.x * a.x + a.y * a.y + a.z * a.z + a.w * a.w;
                q1 += bb.x * bb.x + bb.y * bb.y + bb.z * bb.z + bb.w * bb.w;
                q2 += c.x * c.x + c.y * c.y + c.z * c.z + c.w * c.w;
            }
#pragma unroll
            for (int m = 1; m < 16; m <<= 1) {
                q0 += __shfl_xor(q0, m, 64);
                q1 += __shfl_xor(q1, m, 64);
                q2 += __shfl_xor(q2, m, 64);
            }
            if (sl == 0) {
                float vm = (sqrtf(q0) + sqrtf(q1) + sqrtf(q2)) * (1.f / 3.f);
                float vf = silu_f(vm * w0);
                float nv = vf / fmaxf(fabsf(vf), NEPS);
                int f = fid[i];
                atomicAdd(&vsum[f], vm);
                atomicAdd(&vfsum[f], vf);
                atomicAdd(&nvsum[f], nv);
            }
        }
        return;
    }

    // ---------------- GEMM role (R18 body) ----------------
    int r0 = (b >> 1) * 64;

    if (tid < 64) {
        int gi = order[r0 + tid];
        ridS[tid] = gi;
        fragS[tid] = fid[gi];
    }
    __syncthreads();

    // A stage: each wave owns 16 rows; per instruction ONE full 1KB row
    {
        const float4* A4 = (const float4*)A;
        int kcL = lane >> 4, c4L = lane & 15;
#pragma unroll
        for (int jb = 0; jb < 2; ++jb) {
            float4 v[8];
#pragma unroll
            for (int j = 0; j < 8; ++j) {
                int row = wid * 16 + jb * 8 + j;
                v[j] = A4[(size_t)ridS[row] * 64 + lane];
            }
#pragma unroll
            for (int j = 0; j < 8; ++j) {
                int row = wid * 16 + jb * 8 + j;
                float s1 = v[j].x + v[j].y + v[j].z + v[j].w;
                float s2 = v[j].x * v[j].x + v[j].y * v[j].y +
                           v[j].z * v[j].z + v[j].w * v[j].w;
#pragma unroll
                for (int m = 32; m; m >>= 1) {
                    s1 += __shfl_xor(s1, m, 64);
                    s2 += __shfl_xor(s2, m, 64);
                }
                if (lane == 0) {
                    float mu_ = s1 * (1.f / HD);
                    float var = s2 * (1.f / HD) - mu_ * mu_;
                    muS[row] = mu_;
                    rsS[row] = rsqrtf(var + LN_EPS);
                }
                ushort4 pk;
                pk.x = f2b(v[j].x); pk.y = f2b(v[j].y);
                pk.z = f2b(v[j].z); pk.w = f2b(v[j].w);
                int slot = row * 32 + kcL * 8 + ((c4L >> 1) ^ (row & 7));
                ((ushort4*)&As16[slot])[c4L & 1] = pk;
            }
        }
    }
    __syncthreads();   // A tile + muS ready

    // MFMA phase: B fragments straight from L2-resident Gbf
    int lg = lane >> 4;
    const unsigned short* bp[4];
#pragma unroll
    for (int ni = 0; ni < 4; ++ni)
        bp[ni] = Gbf + (size_t)(wid * 64 + ni * 16 + (lane & 15)) * HD + lg * 8;

    f32x4 acc[4][4] = {};
#pragma unroll
    for (int kc = 0; kc < 4; ++kc) {
        short8 bfr[2][4];
#pragma unroll
        for (int kk = 0; kk < 2; ++kk)
#pragma unroll
            for (int ni = 0; ni < 4; ++ni)
                bfr[kk][ni] = *(const short8*)(bp[ni] + kc * 64 + kk * 32);
#pragma unroll
        for (int kk = 0; kk < 2; ++kk) {
            int jp = kk * 4 + lg;
            short8 a[4];
#pragma unroll
            for (int mi = 0; mi < 4; ++mi) {
                int r = mi * 16 + (lane & 15);
                F4S8 t_; t_.f = As16[r * 32 + kc * 8 + (jp ^ (r & 7))];
                a[mi] = t_.s;
            }
#pragma unroll
            for (int mi = 0; mi < 4; ++mi)
#pragma unroll
                for (int ni = 0; ni < 4; ++ni)
                    acc[mi][ni] = __builtin_amdgcn_mfma_f32_16x16x32_bf16(
                        a[mi], bfr[kk][ni], acc[mi][ni], 0, 0, 0);
        }
    }
    __syncthreads();   // all waves done reading As16 -> safe to reuse as feat

    float sv[4], cv[4];
#pragma unroll
    for (int ni = 0; ni < 4; ++ni) {
        int c = wid * 64 + ni * 16 + (lane & 15);
        sv[ni] = svec[c];
        cv[ni] = c0[c];
    }
    // epilogue: affine + silu -> feat tile in LDS (reuses As16) + per-row sq
    unsigned short* featS = (unsigned short*)As16;
    float sq[4][4];
#pragma unroll
    for (int mi = 0; mi < 4; ++mi)
#pragma unroll
        for (int q = 0; q < 4; ++q) {
            int rl = mi * 16 + (lane >> 4) * 4 + q;
            float mu_ = muS[rl], rs_ = rsS[rl];
            float sqa = 0.f;
#pragma unroll
            for (int ni = 0; ni < 4; ++ni) {
                int c = wid * 64 + ni * 16 + (lane & 15);
                float pre = rs_ * (acc[mi][ni][q] - mu_ * sv[ni]) + cv[ni];
                unsigned short us = f2b(silu_f(pre));
                featS[rl * 256 + (c ^ ((rl & 7) << 2))] = us;
                float fr = b2f(us);
                sqa += fr * fr;
            }
            sq[mi][q] = sqa;
        }
#pragma unroll
    for (int mi = 0; mi < 4; ++mi)
#pragma unroll
        for (int q = 0; q < 4; ++q) {
            float s_ = sq[mi][q];
            s_ += __shfl_xor(s_, 1, 64);
            s_ += __shfl_xor(s_, 2, 64);
            s_ += __shfl_xor(s_, 4, 64);
            s_ += __shfl_xor(s_, 8, 64);
            if ((lane & 15) == 0) sqL[mi * 16 + (lane >> 4) * 4 + q][wid] = s_;
        }
    __syncthreads();
    if (tid < 64) {
        float t = sqL[tid][0] + sqL[tid][1] + sqL[tid][2] + sqL[tid][3];
        rnS[tid] = 1.f / fmaxf(sqrtf(t), NEPS);
    }
    __syncthreads();
    // fragment-segment accumulation: one column per thread, scan 64 rows
    int cc = wid * 64 + lane;
    float sAcc = 0.f, nAcc = 0.f;
    int curF = fragS[0];
    for (int row = 0; row < 64; ++row) {
        int f = fragS[row];
        if (f != curF) {
            int gs = offs[curF], n = cnt[curF];
            if (gs >= r0 && gs + n <= r0 + 64) {
                ssum[(size_t)curF * HD + cc] = sAcc;
                nsum[(size_t)curF * HD + cc] = nAcc;
            } else {
                atomicAdd(&ssum[(size_t)curF * HD + cc], sAcc);
                atomicAdd(&nsum[(size_t)curF * HD + cc], nAcc);
            }
            sAcc = 0.f; nAcc = 0.f; curF = f;
        }
        float v = b2f(featS[row * 256 + (cc ^ ((row & 7) << 2))]);
        sAcc += v;
        nAcc = fmaf(v, rnS[row], nAcc);
    }
    {
        int gs = offs[curF], n = cnt[curF];
        if (gs >= r0 && gs + n <= r0 + 64) {
            ssum[(size_t)curF * HD + cc] = sAcc;
            nsum[(size_t)curF * HD + cc] = nAcc;
        } else {
            atomicAdd(&ssum[(size_t)curF * HD + cc], sAcc);
            atomicAdd(&nsum[(size_t)curF * HD + cc], nAcc);
        }
    }
}

// ---------------- fragment pass: block partials, NO global atomics ---------
__global__ __launch_bounds__(256) void k_frag(
    const float* __restrict__ ssum, const float* __restrict__ nsum,
    const int* __restrict__ cnt, const float* __restrict__ vsum,
    const float* __restrict__ vfsum, const float* __restrict__ nvsum,
    double* __restrict__ partial) {
    __shared__ double lred[4][PSTRIDE];
    int tid = threadIdx.x;
    int lane = tid & 63, wid = tid >> 6;
    int gwave = blockIdx.x * 4 + wid;
    const int nw = FRAGB * 4;

    double la0 = 0, la1 = 0, la2 = 0, la3 = 0;
    double lv = 0, ltr = 0, lvc = 0, ldS = 0, ldV = 0;

    for (int f = gwave; f < NF; f += nw) {
        float4 s = ((const float4*)(ssum + (size_t)f * HD))[lane];
        float4 nn = ((const float4*)(nsum + (size_t)f * HD))[lane];
        int c = cnt[f];
        float ssq = s.x * s.x + s.y * s.y + s.z * s.z + s.w * s.w;
        float dsn = nn.x * s.x + nn.y * s.y + nn.z * s.z + nn.w * s.w;
#pragma unroll
        for (int m = 32; m; m >>= 1) {
            ssq += __shfl_xor(ssq, m, 64);
            dsn += __shfl_xor(dsn, m, 64);
        }
        float inv_all = 1.f / fmaxf((float)c, 1.f);
        float m0 = s.x * inv_all, m1 = s.y * inv_all, m2 = s.z * inv_all, m3 = s.w * inv_all;
        float ssq_mean = ssq * inv_all * inv_all;
        float vfr = vsum[f] * inv_all;
        float nrm2 = ssq_mean + vfr * vfr;
        float inv = 1.f / fmaxf(sqrtf(nrm2), NEPS);
        la0 += (double)(m0 * inv);
        la1 += (double)(m1 * inv);
        la2 += (double)(m2 * inv);
        la3 += (double)(m3 * inv);
        if (lane == 0) {
            lv += (double)(vfr * inv);
            ltr += (double)(nrm2 * inv * inv);
            if (c >= MINFRAG) {
                lvc += (double)c;
                float denom = fmaxf(sqrtf(ssq), NEPS);
                ldS += (double)c - (double)(dsn / denom);
                float vfm = vfsum[f] * inv_all;
                float vsgn = vfm / fmaxf(fabsf(vfm), NEPS);
                ldV += (double)c - (double)(vsgn * nvsum[f]);
            }
        }
    }
    lred[wid][4 * lane + 0] = la0;
    lred[wid][4 * lane + 1] = la1;
    lred[wid][4 * lane + 2] = la2;
    lred[wid][4 * lane + 3] = la3;
    if (lane == 0) {
        lred[wid][256] = lv;
        lred[wid][IDX_TRACE] = ltr;
        lred[wid][IDX_DEVS] = ldS;
        lred[wid][IDX_DEVV] = ldV;
        lred[wid][IDX_VCNT] = lvc;
    }
    __syncthreads();
    for (int idx = tid; idx < 261; idx += 256)
        partial[(size_t)blockIdx.x * PSTRIDE + idx] =
            lred[0][idx] + lred[1][idx] + lred[2][idx] + lred[3][idx];
}

// ---------------- final: sum block partials + combine ----------------
__global__ __launch_bounds__(256) void k_final(const double* __restrict__ partial,
                                               float* __restrict__ out) {
    __shared__ double fin[PSTRIDE];
    int t = threadIdx.x;
    for (int idx = t; idx < 261; idx += 256) {
        double s = 0;
        for (int b = 0; b < FRAGB; ++b) s += partial[(size_t)b * PSTRIDE + idx];
        fin[idx] = s;
    }
    __syncthreads();
    if (t == 0) {
        double s2 = 0;
        for (int d = 0; d < 257; ++d) s2 += fin[d] * fin[d];
        double off = s2 - fin[IDX_TRACE];
        double inter = off / ((double)NF * NF - NF + 1e-6);
        double vc = fmax(fin[IDX_VCNT], 1.0);
        double total = fin[IDX_DEVS] / vc + fin[IDX_DEVV] / vc + 0.2 * inter;
        out[0] = (float)(0.03 * 0.05 * total);
    }
}

extern "C" void kernel_launch(void* const* d_in, const int* in_sizes, int n_in,
                              void* d_out, int out_size, void* d_ws, size_t ws_size,
                              hipStream_t stream) {
    const float* scalar_short = (const float*)d_in[0];
    const float* vector_short = (const float*)d_in[2];
    const int* fragment_ids = (const int*)d_in[4];
    const float* ln_gamma = (const float*)d_in[5];
    const float* ln_beta = (const float*)d_in[6];
    const float* W1 = (const float*)d_in[7];
    const float* b1 = (const float*)d_in[8];
    const float* Wv = (const float*)d_in[9];
    float* out = (float*)d_out;

    char* ws = (char*)d_ws;
    int* cnt = (int*)(ws + OFF_CNT);
    float* vsum = (float*)(ws + OFF_VSUM);
    float* vfsum = (float*)(ws + OFF_VFSUM);
    float* nvsum = (float*)(ws + OFF_NVSUM);
    int* fill = (int*)(ws + OFF_FILL);
    float* ssum = (float*)(ws + OFF_SSUM);
    float* nsum = (float*)(ws + OFF_NSUM);
    int* offs = (int*)(ws + OFF_OFFS);
    float* svec = (float*)(ws + OFF_SVEC);
    float* c0 = (float*)(ws + OFF_C0);
    float* w0 = (float*)(ws + OFF_W0);
    unsigned short* Gbf = (unsigned short*)(ws + OFF_GBF);
    int* order = (int*)(ws + OFF_ORDER);
    double* partial = (double*)(ws + OFF_PART);

    k_prep<<<2069, 256, 0, stream>>>(W1, ln_gamma, ln_beta, b1, Wv, Gbf, svec,
                                     c0, w0, (float4*)ws);
    k_hist<<<NA / 256, 256, 0, stream>>>(fragment_ids, cnt);
    k_scan<<<1, 256, 0, stream>>>(cnt, offs);
    k_scatter<<<NA / 256, 256, 0, stream>>>(fragment_ids, offs, fill, order);
    k_merged<<<4096, 256, 0, stream>>>(scalar_short, Gbf, svec, c0,
                                       vector_short, w0, order, fragment_ids,
                                       offs, cnt, vsum, vfsum, nvsum, ssum, nsum);
    k_frag<<<FRAGB, 256, 0, stream>>>(ssum, nsum, cnt, vsum, vfsum, nvsum, partial);
    k_final<<<1, 256, 0, stream>>>(partial, out);
}

// Round 20
// 214.219 us; speedup vs baseline: 1.0634x; 1.0634x over previous
//
#include <hip/hip_runtime.h>
#include <hip/hip_bf16.h>
#include <stdint.h>

#define NA 131072
#define HD 256
#define NF 4096
#define MINFRAG 3
#define LN_EPS 1e-5f
#define NEPS 1e-12f

// ---- workspace layout (bytes) ----
// zeroed region [0, ZERO_BYTES) via k_prep (fused zero, 2069 blocks)
#define OFF_CNT    0ull          // NF i32
#define OFF_VSUM   16384ull      // NF f32
#define OFF_VFSUM  32768ull      // NF f32
#define OFF_NVSUM  49152ull      // NF f32
#define OFF_FILL   65536ull      // NF i32
#define OFF_DBL    81920ull      // unused (layout keep)
#define OFF_SSUM   86016ull      // NF*HD f32 = 4194304
#define OFF_NSUM   4280320ull    // NF*HD f32 = 4194304
#define ZERO_BYTES 8474624ull    // = 529664 float4 = 2069*256
// non-zeroed
#define OFF_OFFS   8474624ull    // NF i32
#define OFF_SVEC   8491008ull    // HD f32
#define OFF_C0     8492032ull    // HD f32
#define OFF_W0     8493056ull    // 1 f32
#define OFF_GBF    8493568ull    // HD*HD bf16 = 131072
#define OFF_ORDER  8624640ull    // NA i32 = 524288
#define OFF_PART   9150464ull    // FRAGB * PSTRIDE doubles
// total: 9,691,136 bytes

#define IDX_TRACE 257
#define IDX_DEVS  258
#define IDX_DEVV  259
#define IDX_VCNT  260
#define FRAGB 256
#define PSTRIDE 264

typedef __attribute__((ext_vector_type(8))) short short8;
typedef __attribute__((ext_vector_type(4))) float f32x4;
union F4S8 { float4 f; short8 s; };
union BFU { __hip_bfloat16 b; unsigned short u; };

__device__ __forceinline__ unsigned short f2b(float x) {
    BFU t; t.b = __float2bfloat16(x); return t.u;
}
__device__ __forceinline__ float b2f(unsigned short u) {
    return __uint_as_float(((uint32_t)u) << 16);
}
// fast silu: native v_exp + v_rcp (rel err ~1e-7, error budget ~1e-2)
__device__ __forceinline__ float silu_f(float x) {
    return x * __builtin_amdgcn_rcpf(1.f + __expf(-x));
}

// ---------------- prep (+ fused workspace zero), 2069 blocks ---------------
__global__ __launch_bounds__(256) void k_prep(
    const float* __restrict__ W1, const float* __restrict__ gamma,
    const float* __restrict__ beta, const float* __restrict__ b1,
    const float* __restrict__ Wv,
    unsigned short* __restrict__ Gbf, float* __restrict__ svec,
    float* __restrict__ c0, float* __restrict__ w0, float4* __restrict__ z) {
    __shared__ float red[8];
    int o = blockIdx.x;       // 2069 blocks
    int t = threadIdx.x;
    {   // zero [0, ZERO_BYTES): 2069*256 float4 exactly
        float4 zv = {0.f, 0.f, 0.f, 0.f};
        z[o * 256 + t] = zv;
    }
    if (o < HD) {
        float w = W1[(size_t)o * HD + t];
        unsigned short gb = f2b(w * gamma[t]);
        Gbf[(size_t)o * HD + t] = gb;
        float sp = b2f(gb);
        float cp = w * beta[t];
#pragma unroll
        for (int m = 32; m; m >>= 1) { sp += __shfl_xor(sp, m, 64); cp += __shfl_xor(cp, m, 64); }
        int wv = t >> 6;
        if ((t & 63) == 0) { red[wv] = sp; red[4 + wv] = cp; }
        __syncthreads();
        if (t == 0) {
            svec[o] = red[0] + red[1] + red[2] + red[3];
            c0[o]   = red[4] + red[5] + red[6] + red[7] + b1[o];
        }
    } else if (o == HD) {
        float v = Wv[t];
#pragma unroll
        for (int m = 32; m; m >>= 1) v += __shfl_xor(v, m, 64);
        int wv = t >> 6;
        if ((t & 63) == 0) red[wv] = v;
        __syncthreads();
        if (t == 0) w0[0] = red[0] + red[1] + red[2] + red[3];
    }
}

// ---- stats: 16-lane groups (4 atoms/wave-iter), contiguous 256B segments --
__global__ __launch_bounds__(256) void k_stats(
    const float* __restrict__ vs, const int* __restrict__ fid,
    const float* __restrict__ w0p,
    int* __restrict__ cnt, float* __restrict__ vsum,
    float* __restrict__ vfsum, float* __restrict__ nvsum) {
    int gwave = (blockIdx.x * blockDim.x + threadIdx.x) >> 6;
    int lane = threadIdx.x & 63;
    int nw = (gridDim.x * blockDim.x) >> 6;
    int g = lane >> 4, sl = lane & 15;
    float w0 = w0p[0];
    for (int i0 = gwave * 4; i0 < NA; i0 += nw * 4) {
        int i = i0 + g;
        const float* vb = vs + (size_t)i * 3 * HD;
        float q0 = 0.f, q1 = 0.f, q2 = 0.f;
#pragma unroll
        for (int j = 0; j < 4; ++j) {
            float4 a = ((const float4*)(vb))[j * 16 + sl];
            float4 b = ((const float4*)(vb + HD))[j * 16 + sl];
            float4 c = ((const float4*)(vb + 2 * HD))[j * 16 + sl];
            q0 += a.x * a.x + a.y * a.y + a.z * a.z + a.w * a.w;
            q1 += b.x * b.x + b.y * b.y + b.z * b.z + b.w * b.w;
            q2 += c.x * c.x + c.y * c.y + c.z * c.z + c.w * c.w;
        }
#pragma unroll
        for (int m = 1; m < 16; m <<= 1) {
            q0 += __shfl_xor(q0, m, 64);
            q1 += __shfl_xor(q1, m, 64);
            q2 += __shfl_xor(q2, m, 64);
        }
        if (sl == 0) {
            float vm = (sqrtf(q0) + sqrtf(q1) + sqrtf(q2)) * (1.f / 3.f);
            float vf = silu_f(vm * w0);
            float nv = vf / fmaxf(fabsf(vf), NEPS);
            int f = fid[i];
            atomicAdd(&cnt[f], 1);
            atomicAdd(&vsum[f], vm);
            atomicAdd(&vfsum[f], vf);
            atomicAdd(&nvsum[f], nv);
        }
    }
}

// ---------------- scan ----------------
__global__ __launch_bounds__(256) void k_scan(const int* __restrict__ cnt,
                                              int* __restrict__ offs) {
    __shared__ int wsum[4];
    int t = threadIdx.x;
    int base = t * 16;
    int c[16];
    int tot = 0;
#pragma unroll
    for (int j = 0; j < 16; ++j) { c[j] = cnt[base + j]; tot += c[j]; }
    int lane = t & 63, w = t >> 6;
    int v = tot;
#pragma unroll
    for (int d = 1; d < 64; d <<= 1) {
        int o = __shfl_up(v, d, 64);
        if (lane >= d) v += o;
    }
    if (lane == 63) wsum[w] = v;
    __syncthreads();
    int wbase = 0;
    for (int i = 0; i < w; ++i) wbase += wsum[i];
    int run = wbase + v - tot;
#pragma unroll
    for (int j = 0; j < 16; ++j) { offs[base + j] = run; run += c[j]; }
}

// ---------------- scatter ----------------
__global__ __launch_bounds__(256) void k_scatter(
    const int* __restrict__ fid, const int* __restrict__ offs,
    int* __restrict__ fill, int* __restrict__ order) {
    int i = blockIdx.x * blockDim.x + threadIdx.x;
    if (i < NA) {
        int f = fid[i];
        int p = atomicAdd(&fill[f], 1);
        order[offs[f] + p] = i;
    }
}

// ---- GEMM: full-row (1KB) per-instruction A gather, B direct from L2 ----
__global__ __launch_bounds__(256) void k_gemm(
    const float* __restrict__ A, const unsigned short* __restrict__ Gbf,
    const float* __restrict__ svec, const float* __restrict__ c0,
    const int* __restrict__ order, const int* __restrict__ fid,
    const int* __restrict__ offs, const int* __restrict__ cnt,
    float* __restrict__ ssum, float* __restrict__ nsum) {
    __shared__ float4 As16[64 * 32];    // 32 KB: full A tile bf16, xor-swizzled
    __shared__ float muS[64], rsS[64], rnS[64];
    __shared__ float sqL[64][4];
    __shared__ int ridS[64], fragS[64];

    int tid = threadIdx.x;
    int lane = tid & 63, wid = tid >> 6;
    int r0 = blockIdx.x * 64;

    if (tid < 64) {
        int gi = order[r0 + tid];
        ridS[tid] = gi;
        fragS[tid] = fid[gi];
    }
    __syncthreads();

    // ---- A stage: each wave owns 16 rows; per instruction ONE full 1KB row
    //      (64 lanes x 16B contiguous = single HBM burst per row) ----
    {
        const float4* A4 = (const float4*)A;
        int kcL = lane >> 4, c4L = lane & 15;
#pragma unroll
        for (int jb = 0; jb < 2; ++jb) {
            float4 v[8];
#pragma unroll
            for (int j = 0; j < 8; ++j) {
                int row = wid * 16 + jb * 8 + j;
                v[j] = A4[(size_t)ridS[row] * 64 + lane];
            }
#pragma unroll
            for (int j = 0; j < 8; ++j) {
                int row = wid * 16 + jb * 8 + j;
                float s1 = v[j].x + v[j].y + v[j].z + v[j].w;
                float s2 = v[j].x * v[j].x + v[j].y * v[j].y +
                           v[j].z * v[j].z + v[j].w * v[j].w;
#pragma unroll
                for (int m = 32; m; m >>= 1) {
                    s1 += __shfl_xor(s1, m, 64);
                    s2 += __shfl_xor(s2, m, 64);
                }
                if (lane == 0) {
                    float mu_ = s1 * (1.f / HD);
                    float var = s2 * (1.f / HD) - mu_ * mu_;
                    muS[row] = mu_;
                    rsS[row] = rsqrtf(var + LN_EPS);
                }
                ushort4 pk;
                pk.x = f2b(v[j].x); pk.y = f2b(v[j].y);
                pk.z = f2b(v[j].z); pk.w = f2b(v[j].w);
                int slot = row * 32 + kcL * 8 + ((c4L >> 1) ^ (row & 7));
                ((ushort4*)&As16[slot])[c4L & 1] = pk;
            }
        }
    }
    __syncthreads();   // A tile + muS ready

    // ---- MFMA phase: B fragments straight from L2-resident Gbf ----
    int lg = lane >> 4;
    const unsigned short* bp[4];
#pragma unroll
    for (int ni = 0; ni < 4; ++ni)
        bp[ni] = Gbf + (size_t)(wid * 64 + ni * 16 + (lane & 15)) * HD + lg * 8;

    f32x4 acc[4][4] = {};
#pragma unroll
    for (int kc = 0; kc < 4; ++kc) {
        short8 bfr[2][4];
#pragma unroll
        for (int kk = 0; kk < 2; ++kk)
#pragma unroll
            for (int ni = 0; ni < 4; ++ni)
                bfr[kk][ni] = *(const short8*)(bp[ni] + kc * 64 + kk * 32);
#pragma unroll
        for (int kk = 0; kk < 2; ++kk) {
            int jp = kk * 4 + lg;
            short8 a[4];
#pragma unroll
            for (int mi = 0; mi < 4; ++mi) {
                int r = mi * 16 + (lane & 15);
                F4S8 t_; t_.f = As16[r * 32 + kc * 8 + (jp ^ (r & 7))];
                a[mi] = t_.s;
            }
#pragma unroll
            for (int mi = 0; mi < 4; ++mi)
#pragma unroll
                for (int ni = 0; ni < 4; ++ni)
                    acc[mi][ni] = __builtin_amdgcn_mfma_f32_16x16x32_bf16(
                        a[mi], bfr[kk][ni], acc[mi][ni], 0, 0, 0);
        }
    }
    __syncthreads();   // all waves done reading As16 -> safe to reuse as feat

    float sv[4], cv[4];
#pragma unroll
    for (int ni = 0; ni < 4; ++ni) {
        int c = wid * 64 + ni * 16 + (lane & 15);
        sv[ni] = svec[c];
        cv[ni] = c0[c];
    }
    // epilogue: affine + silu -> feat tile in LDS (reuses As16) + per-row sq
    unsigned short* featS = (unsigned short*)As16;
    float sq[4][4];
#pragma unroll
    for (int mi = 0; mi < 4; ++mi)
#pragma unroll
        for (int q = 0; q < 4; ++q) {
            int rl = mi * 16 + (lane >> 4) * 4 + q;
            float mu_ = muS[rl], rs_ = rsS[rl];
            float sqa = 0.f;
#pragma unroll
            for (int ni = 0; ni < 4; ++ni) {
                int c = wid * 64 + ni * 16 + (lane & 15);
                float pre = rs_ * (acc[mi][ni][q] - mu_ * sv[ni]) + cv[ni];
                unsigned short us = f2b(silu_f(pre));
                featS[rl * 256 + (c ^ ((rl & 7) << 2))] = us;
                float fr = b2f(us);
                sqa += fr * fr;
            }
            sq[mi][q] = sqa;
        }
#pragma unroll
    for (int mi = 0; mi < 4; ++mi)
#pragma unroll
        for (int q = 0; q < 4; ++q) {
            float s_ = sq[mi][q];
            s_ += __shfl_xor(s_, 1, 64);
            s_ += __shfl_xor(s_, 2, 64);
            s_ += __shfl_xor(s_, 4, 64);
            s_ += __shfl_xor(s_, 8, 64);
            if ((lane & 15) == 0) sqL[mi * 16 + (lane >> 4) * 4 + q][wid] = s_;
        }
    __syncthreads();
    if (tid < 64) {
        float t = sqL[tid][0] + sqL[tid][1] + sqL[tid][2] + sqL[tid][3];
        rnS[tid] = 1.f / fmaxf(sqrtf(t), NEPS);
    }
    __syncthreads();
    // fragment-segment accumulation: one column per thread, scan 64 rows
    int cc = wid * 64 + lane;
    float sAcc = 0.f, nAcc = 0.f;
    int curF = fragS[0];
    for (int row = 0; row < 64; ++row) {
        int f = fragS[row];
        if (f != curF) {
            int gs = offs[curF], n = cnt[curF];
            if (gs >= r0 && gs + n <= r0 + 64) {
                ssum[(size_t)curF * HD + cc] = sAcc;
                nsum[(size_t)curF * HD + cc] = nAcc;
            } else {
                atomicAdd(&ssum[(size_t)curF * HD + cc], sAcc);
                atomicAdd(&nsum[(size_t)curF * HD + cc], nAcc);
            }
            sAcc = 0.f; nAcc = 0.f; curF = f;
        }
        float v = b2f(featS[row * 256 + (cc ^ ((row & 7) << 2))]);
        sAcc += v;
        nAcc = fmaf(v, rnS[row], nAcc);
    }
    {
        int gs = offs[curF], n = cnt[curF];
        if (gs >= r0 && gs + n <= r0 + 64) {
            ssum[(size_t)curF * HD + cc] = sAcc;
            nsum[(size_t)curF * HD + cc] = nAcc;
        } else {
            atomicAdd(&ssum[(size_t)curF * HD + cc], sAcc);
            atomicAdd(&nsum[(size_t)curF * HD + cc], nAcc);
        }
    }
}

// ---------------- fragment pass: block partials, NO global atomics ---------
__global__ __launch_bounds__(256) void k_frag(
    const float* __restrict__ ssum, const float* __restrict__ nsum,
    const int* __restrict__ cnt, const float* __restrict__ vsum,
    const float* __restrict__ vfsum, const float* __restrict__ nvsum,
    double* __restrict__ partial) {
    __shared__ double lred[4][PSTRIDE];
    int tid = threadIdx.x;
    int lane = tid & 63, wid = tid >> 6;
    int gwave = blockIdx.x * 4 + wid;
    const int nw = FRAGB * 4;

    double la0 = 0, la1 = 0, la2 = 0, la3 = 0;
    double lv = 0, ltr = 0, lvc = 0, ldS = 0, ldV = 0;

    for (int f = gwave; f < NF; f += nw) {
        float4 s = ((const float4*)(ssum + (size_t)f * HD))[lane];
        float4 nn = ((const float4*)(nsum + (size_t)f * HD))[lane];
        int c = cnt[f];
        float ssq = s.x * s.x + s.y * s.y + s.z * s.z + s.w * s.w;
        float dsn = nn.x * s.x + nn.y * s.y + nn.z * s.z + nn.w * s.w;
#pragma unroll
        for (int m = 32; m; m >>= 1) {
            ssq += __shfl_xor(ssq, m, 64);
            dsn += __shfl_xor(dsn, m, 64);
        }
        float inv_all = 1.f / fmaxf((float)c, 1.f);
        float m0 = s.x * inv_all, m1 = s.y * inv_all, m2 = s.z * inv_all, m3 = s.w * inv_all;
        float ssq_mean = ssq * inv_all * inv_all;
        float vfr = vsum[f] * inv_all;
        float nrm2 = ssq_mean + vfr * vfr;
        float inv = 1.f / fmaxf(sqrtf(nrm2), NEPS);
        la0 += (double)(m0 * inv);
        la1 += (double)(m1 * inv);
        la2 += (double)(m2 * inv);
        la3 += (double)(m3 * inv);
        if (lane == 0) {
            lv += (double)(vfr * inv);
            ltr += (double)(nrm2 * inv * inv);
            if (c >= MINFRAG) {
                lvc += (double)c;
                float denom = fmaxf(sqrtf(ssq), NEPS);
                ldS += (double)c - (double)(dsn / denom);
                float vfm = vfsum[f] * inv_all;
                float vsgn = vfm / fmaxf(fabsf(vfm), NEPS);
                ldV += (double)c - (double)(vsgn * nvsum[f]);
            }
        }
    }
    lred[wid][4 * lane + 0] = la0;
    lred[wid][4 * lane + 1] = la1;
    lred[wid][4 * lane + 2] = la2;
    lred[wid][4 * lane + 3] = la3;
    if (lane == 0) {
        lred[wid][256] = lv;
        lred[wid][IDX_TRACE] = ltr;
        lred[wid][IDX_DEVS] = ldS;
        lred[wid][IDX_DEVV] = ldV;
        lred[wid][IDX_VCNT] = lvc;
    }
    __syncthreads();
    for (int idx = tid; idx < 261; idx += 256)
        partial[(size_t)blockIdx.x * PSTRIDE + idx] =
            lred[0][idx] + lred[1][idx] + lred[2][idx] + lred[3][idx];
}

// ---------------- final: sum block partials + combine ----------------
__global__ __launch_bounds__(256) void k_final(const double* __restrict__ partial,
                                               float* __restrict__ out) {
    __shared__ double fin[PSTRIDE];
    int t = threadIdx.x;
    for (int idx = t; idx < 261; idx += 256) {
        double s = 0;
        for (int b = 0; b < FRAGB; ++b) s += partial[(size_t)b * PSTRIDE + idx];
        fin[idx] = s;
    }
    __syncthreads();
    if (t == 0) {
        double s2 = 0;
        for (int d = 0; d < 257; ++d) s2 += fin[d] * fin[d];
        double off = s2 - fin[IDX_TRACE];
        double inter = off / ((double)NF * NF - NF + 1e-6);
        double vc = fmax(fin[IDX_VCNT], 1.0);
        double total = fin[IDX_DEVS] / vc + fin[IDX_DEVV] / vc + 0.2 * inter;
        out[0] = (float)(0.03 * 0.05 * total);
    }
}

extern "C" void kernel_launch(void* const* d_in, const int* in_sizes, int n_in,
                              void* d_out, int out_size, void* d_ws, size_t ws_size,
                              hipStream_t stream) {
    const float* scalar_short = (const float*)d_in[0];
    const float* vector_short = (const float*)d_in[2];
    const int* fragment_ids = (const int*)d_in[4];
    const float* ln_gamma = (const float*)d_in[5];
    const float* ln_beta = (const float*)d_in[6];
    const float* W1 = (const float*)d_in[7];
    const float* b1 = (const float*)d_in[8];
    const float* Wv = (const float*)d_in[9];
    float* out = (float*)d_out;

    char* ws = (char*)d_ws;
    int* cnt = (int*)(ws + OFF_CNT);
    float* vsum = (float*)(ws + OFF_VSUM);
    float* vfsum = (float*)(ws + OFF_VFSUM);
    float* nvsum = (float*)(ws + OFF_NVSUM);
    int* fill = (int*)(ws + OFF_FILL);
    float* ssum = (float*)(ws + OFF_SSUM);
    float* nsum = (float*)(ws + OFF_NSUM);
    int* offs = (int*)(ws + OFF_OFFS);
    float* svec = (float*)(ws + OFF_SVEC);
    float* c0 = (float*)(ws + OFF_C0);
    float* w0 = (float*)(ws + OFF_W0);
    unsigned short* Gbf = (unsigned short*)(ws + OFF_GBF);
    int* order = (int*)(ws + OFF_ORDER);
    double* partial = (double*)(ws + OFF_PART);

    k_prep<<<2069, 256, 0, stream>>>(W1, ln_gamma, ln_beta, b1, Wv, Gbf, svec,
                                     c0, w0, (float4*)ws);
    k_stats<<<8192, 256, 0, stream>>>(vector_short, fragment_ids, w0, cnt, vsum, vfsum, nvsum);
    k_scan<<<1, 256, 0, stream>>>(cnt, offs);
    k_scatter<<<NA / 256, 256, 0, stream>>>(fragment_ids, offs, fill, order);
    k_gemm<<<NA / 64, 256, 0, stream>>>(scalar_short, Gbf, svec, c0, order,
                                        fragment_ids, offs, cnt, ssum, nsum);
    k_frag<<<FRAGB, 256, 0, stream>>>(ssum, nsum, cnt, vsum, vfsum, nvsum, partial);
    k_final<<<1, 256, 0, stream>>>(partial, out);
}